// Round 8
// baseline (141.767 us; speedup 1.0000x reference)
//
#include <hip/hip_runtime.h>
#include <math.h>

#define NS 4
#define SINKHORN_ITERS 10
#define TAU 0.05f

// T*D/4 in float4 units: 4096*2048/4 = 2^21
#define PLANE4 2097152L
#define PLANE4_SHIFT 21
#define NTHREADS (1 << 20)   // 4096 blocks x 256 threads

typedef float f32x4 __attribute__((ext_vector_type(4)));

// ---------------------------------------------------------------------------
// Kernel 1: compute M[4][4] = H_res^T + H_post (outer) H_pre  into d_ws.
// ---------------------------------------------------------------------------
__global__ void hc_coef_kernel(const float* __restrict__ Hres_logits,
                               const float* __restrict__ Hpre_logits,
                               const float* __restrict__ Hpost_logits,
                               float* __restrict__ M) {
    if (threadIdx.x != 0 || blockIdx.x != 0) return;

    float Z[NS][NS], u[NS], v[NS];
    for (int i = 0; i < NS; ++i)
        for (int j = 0; j < NS; ++j)
            Z[i][j] = Hres_logits[i * NS + j] / TAU;

    const float logm = -logf((float)NS);
    for (int i = 0; i < NS; ++i) { u[i] = 0.f; v[i] = 0.f; }

    for (int it = 0; it < SINKHORN_ITERS; ++it) {
        for (int i = 0; i < NS; ++i) {
            float mx = -INFINITY;
            for (int j = 0; j < NS; ++j) mx = fmaxf(mx, Z[i][j] + v[j]);
            float s = 0.f;
            for (int j = 0; j < NS; ++j) s += expf(Z[i][j] + v[j] - mx);
            u[i] = logm - (mx + logf(s));
        }
        for (int j = 0; j < NS; ++j) {
            float mx = -INFINITY;
            for (int i = 0; i < NS; ++i) mx = fmaxf(mx, Z[i][j] + u[i]);
            float s = 0.f;
            for (int i = 0; i < NS; ++i) s += expf(Z[i][j] + u[i] - mx);
            v[j] = logm - (mx + logf(s));
        }
    }

    float Hres[NS][NS];
    for (int i = 0; i < NS; ++i)
        for (int j = 0; j < NS; ++j)
            Hres[i][j] = expf(Z[i][j] + u[i] + v[j]) * (float)NS;

    float hp[NS], mx = -INFINITY, s = 0.f;
    for (int i = 0; i < NS; ++i) mx = fmaxf(mx, Hpre_logits[i]);
    for (int i = 0; i < NS; ++i) { hp[i] = expf(Hpre_logits[i] - mx); s += hp[i]; }
    for (int i = 0; i < NS; ++i) hp[i] /= s;

    float ho[NS];
    mx = -INFINITY; s = 0.f;
    for (int i = 0; i < NS; ++i) mx = fmaxf(mx, Hpost_logits[i]);
    for (int i = 0; i < NS; ++i) { ho[i] = expf(Hpost_logits[i] - mx); s += ho[i]; }
    for (int i = 0; i < NS; ++i) ho[i] /= s;

    for (int so = 0; so < NS; ++so)
        for (int si = 0; si < NS; ++si)
            M[so * NS + si] = Hres[si][so] + ho[so] * hp[si];
}

// ---------------------------------------------------------------------------
// Kernel 2 (fast path): R7 structure — flat unroll-4, 2^20 threads, thread t
// owns positions t + k*2^20 (k=0..3; b = k>>1 compile-time).
// Single change vs R7: loads are NONTEMPORAL again (NT both sides).
// ---------------------------------------------------------------------------
__global__ __launch_bounds__(256) void hc_mix_flat(
        const f32x4* __restrict__ in,
        const float* __restrict__ Mg,
        f32x4* __restrict__ out) {
    float m[16];
#pragma unroll
    for (int k = 0; k < 16; ++k) m[k] = Mg[k];

    const long gtid = blockIdx.x * blockDim.x + threadIdx.x;

    f32x4 v[4][NS];
#pragma unroll
    for (int k = 0; k < 4; ++k) {
        const long base = (long)(k >> 1) * (NS * PLANE4) + ((long)(k & 1) << 20) + gtid;
#pragma unroll
        for (int s = 0; s < NS; ++s)
            v[k][s] = __builtin_nontemporal_load(&in[base + (long)s * PLANE4]);
    }

#pragma unroll
    for (int k = 0; k < 4; ++k) {
        const long base = (long)(k >> 1) * (NS * PLANE4) + ((long)(k & 1) << 20) + gtid;
#pragma unroll
        for (int o = 0; o < NS; ++o) {
            f32x4 r = m[o*4+0] * v[k][0] + m[o*4+1] * v[k][1] +
                      m[o*4+2] * v[k][2] + m[o*4+3] * v[k][3];
            __builtin_nontemporal_store(r, &out[base + (long)o * PLANE4]);
        }
    }
}

// Generic fallback (any size), same math.
__global__ __launch_bounds__(256) void hc_mix_generic(
        const f32x4* __restrict__ in,
        const float* __restrict__ Mg,
        f32x4* __restrict__ out,
        int npos4) {
    float m[16];
#pragma unroll
    for (int k = 0; k < 16; ++k) m[k] = Mg[k];

    const int stride = gridDim.x * blockDim.x;
    for (int p = blockIdx.x * blockDim.x + threadIdx.x; p < npos4; p += stride) {
        const int b = p >> PLANE4_SHIFT;
        const long base = ((long)(b * NS) << PLANE4_SHIFT) + (p & (PLANE4 - 1));
        const f32x4 v0 = in[base];
        const f32x4 v1 = in[base + PLANE4];
        const f32x4 v2 = in[base + 2 * PLANE4];
        const f32x4 v3 = in[base + 3 * PLANE4];
#pragma unroll
        for (int o = 0; o < NS; ++o) {
            f32x4 r = m[o*4+0]*v0 + m[o*4+1]*v1 + m[o*4+2]*v2 + m[o*4+3]*v3;
            __builtin_nontemporal_store(r, &out[base + (long)o * PLANE4]);
        }
    }
}

extern "C" void kernel_launch(void* const* d_in, const int* in_sizes, int n_in,
                              void* d_out, int out_size, void* d_ws, size_t ws_size,
                              hipStream_t stream) {
    const float* residuals   = (const float*)d_in[0];  // (B*S, T, D) = (8,4096,2048) f32
    const float* Hres_logits = (const float*)d_in[1];  // (4,4)
    const float* Hpre_logits = (const float*)d_in[2];  // (4,)
    const float* Hpost_logits= (const float*)d_in[3];  // (4,)
    float* out = (float*)d_out;
    float* M   = (float*)d_ws;                         // 16 floats

    hc_coef_kernel<<<1, 64, 0, stream>>>(Hres_logits, Hpre_logits, Hpost_logits, M);

    const int npos4 = out_size / (NS * 4);             // B*T*D/4 = 4194304
    if (npos4 == 4 * NTHREADS) {
        hc_mix_flat<<<NTHREADS / 256, 256, 0, stream>>>(
            (const f32x4*)residuals, M, (f32x4*)out);
    } else {
        hc_mix_generic<<<2048, 256, 0, stream>>>(
            (const f32x4*)residuals, M, (f32x4*)out, npos4);
    }
}

// Round 9
// 139.964 us; speedup vs baseline: 1.0129x; 1.0129x over previous
//
#include <hip/hip_runtime.h>
#include <math.h>

#define NS 4
#define SINKHORN_ITERS 10
#define TAU 0.05f

// T*D/4 in float4 units: 4096*2048/4 = 2^21
#define PLANE4 2097152L
#define PLANE4_SHIFT 21
#define NTHREADS (1 << 20)   // 4096 blocks x 256 threads

typedef float f32x4 __attribute__((ext_vector_type(4)));

// ---------------------------------------------------------------------------
// Kernel 1: compute M[4][4] = H_res^T + H_post (outer) H_pre  into d_ws.
// ---------------------------------------------------------------------------
__global__ void hc_coef_kernel(const float* __restrict__ Hres_logits,
                               const float* __restrict__ Hpre_logits,
                               const float* __restrict__ Hpost_logits,
                               float* __restrict__ M) {
    if (threadIdx.x != 0 || blockIdx.x != 0) return;

    float Z[NS][NS], u[NS], v[NS];
    for (int i = 0; i < NS; ++i)
        for (int j = 0; j < NS; ++j)
            Z[i][j] = Hres_logits[i * NS + j] / TAU;

    const float logm = -logf((float)NS);
    for (int i = 0; i < NS; ++i) { u[i] = 0.f; v[i] = 0.f; }

    for (int it = 0; it < SINKHORN_ITERS; ++it) {
        for (int i = 0; i < NS; ++i) {
            float mx = -INFINITY;
            for (int j = 0; j < NS; ++j) mx = fmaxf(mx, Z[i][j] + v[j]);
            float s = 0.f;
            for (int j = 0; j < NS; ++j) s += expf(Z[i][j] + v[j] - mx);
            u[i] = logm - (mx + logf(s));
        }
        for (int j = 0; j < NS; ++j) {
            float mx = -INFINITY;
            for (int i = 0; i < NS; ++i) mx = fmaxf(mx, Z[i][j] + u[i]);
            float s = 0.f;
            for (int i = 0; i < NS; ++i) s += expf(Z[i][j] + u[i] - mx);
            v[j] = logm - (mx + logf(s));
        }
    }

    float Hres[NS][NS];
    for (int i = 0; i < NS; ++i)
        for (int j = 0; j < NS; ++j)
            Hres[i][j] = expf(Z[i][j] + u[i] + v[j]) * (float)NS;

    float hp[NS], mx = -INFINITY, s = 0.f;
    for (int i = 0; i < NS; ++i) mx = fmaxf(mx, Hpre_logits[i]);
    for (int i = 0; i < NS; ++i) { hp[i] = expf(Hpre_logits[i] - mx); s += hp[i]; }
    for (int i = 0; i < NS; ++i) hp[i] /= s;

    float ho[NS];
    mx = -INFINITY; s = 0.f;
    for (int i = 0; i < NS; ++i) mx = fmaxf(mx, Hpost_logits[i]);
    for (int i = 0; i < NS; ++i) { ho[i] = expf(Hpost_logits[i] - mx); s += ho[i]; }
    for (int i = 0; i < NS; ++i) ho[i] /= s;

    for (int so = 0; so < NS; ++so)
        for (int si = 0; si < NS; ++si)
            M[so * NS + si] = Hres[si][so] + ho[so] * hp[si];
}

// ---------------------------------------------------------------------------
// Kernel 2 (fast path): R7 structure — flat unroll-4, 2^20 threads, thread t
// owns positions t + k*2^20 (k=0..3; b = k>>1 compile-time).
// Single change vs R7 (the best config): stores NT -> PLAIN.
// Factorial cell: (plain loads, plain stores).
// ---------------------------------------------------------------------------
__global__ __launch_bounds__(256) void hc_mix_flat(
        const f32x4* __restrict__ in,
        const float* __restrict__ Mg,
        f32x4* __restrict__ out) {
    float m[16];
#pragma unroll
    for (int k = 0; k < 16; ++k) m[k] = Mg[k];

    const long gtid = blockIdx.x * blockDim.x + threadIdx.x;

    f32x4 v[4][NS];
#pragma unroll
    for (int k = 0; k < 4; ++k) {
        const long base = (long)(k >> 1) * (NS * PLANE4) + ((long)(k & 1) << 20) + gtid;
#pragma unroll
        for (int s = 0; s < NS; ++s)
            v[k][s] = in[base + (long)s * PLANE4];
    }

#pragma unroll
    for (int k = 0; k < 4; ++k) {
        const long base = (long)(k >> 1) * (NS * PLANE4) + ((long)(k & 1) << 20) + gtid;
#pragma unroll
        for (int o = 0; o < NS; ++o) {
            out[base + (long)o * PLANE4] =
                m[o*4+0] * v[k][0] + m[o*4+1] * v[k][1] +
                m[o*4+2] * v[k][2] + m[o*4+3] * v[k][3];
        }
    }
}

// Generic fallback (any size), same math.
__global__ __launch_bounds__(256) void hc_mix_generic(
        const f32x4* __restrict__ in,
        const float* __restrict__ Mg,
        f32x4* __restrict__ out,
        int npos4) {
    float m[16];
#pragma unroll
    for (int k = 0; k < 16; ++k) m[k] = Mg[k];

    const int stride = gridDim.x * blockDim.x;
    for (int p = blockIdx.x * blockDim.x + threadIdx.x; p < npos4; p += stride) {
        const int b = p >> PLANE4_SHIFT;
        const long base = ((long)(b * NS) << PLANE4_SHIFT) + (p & (PLANE4 - 1));
        const f32x4 v0 = in[base];
        const f32x4 v1 = in[base + PLANE4];
        const f32x4 v2 = in[base + 2 * PLANE4];
        const f32x4 v3 = in[base + 3 * PLANE4];
#pragma unroll
        for (int o = 0; o < NS; ++o)
            out[base + (long)o * PLANE4] =
                m[o*4+0]*v0 + m[o*4+1]*v1 + m[o*4+2]*v2 + m[o*4+3]*v3;
    }
}

extern "C" void kernel_launch(void* const* d_in, const int* in_sizes, int n_in,
                              void* d_out, int out_size, void* d_ws, size_t ws_size,
                              hipStream_t stream) {
    const float* residuals   = (const float*)d_in[0];  // (B*S, T, D) = (8,4096,2048) f32
    const float* Hres_logits = (const float*)d_in[1];  // (4,4)
    const float* Hpre_logits = (const float*)d_in[2];  // (4,)
    const float* Hpost_logits= (const float*)d_in[3];  // (4,)
    float* out = (float*)d_out;
    float* M   = (float*)d_ws;                         // 16 floats

    hc_coef_kernel<<<1, 64, 0, stream>>>(Hres_logits, Hpre_logits, Hpost_logits, M);

    const int npos4 = out_size / (NS * 4);             // B*T*D/4 = 4194304
    if (npos4 == 4 * NTHREADS) {
        hc_mix_flat<<<NTHREADS / 256, 256, 0, stream>>>(
            (const f32x4*)residuals, M, (f32x4*)out);
    } else {
        hc_mix_generic<<<2048, 256, 0, stream>>>(
            (const f32x4*)residuals, M, (f32x4*)out, npos4);
    }
}

// Round 10
// 100.956 us; speedup vs baseline: 1.4042x; 1.3864x over previous
//
#include <hip/hip_runtime.h>
#include <math.h>

#define NS 4
#define SINKHORN_ITERS 10
#define TAU 0.05f

// T*D/4 in float4 units: 4096*2048/4 = 2^21
#define PLANE4 2097152L
#define PLANE4_SHIFT 21
#define NTHREADS (1 << 20)   // 4096 blocks x 256 threads

typedef float f32x4 __attribute__((ext_vector_type(4)));

// ---------------------------------------------------------------------------
// Kernel 1: compute M[4][4] = H_res^T + H_post (outer) H_pre  into d_ws.
// ---------------------------------------------------------------------------
__global__ void hc_coef_kernel(const float* __restrict__ Hres_logits,
                               const float* __restrict__ Hpre_logits,
                               const float* __restrict__ Hpost_logits,
                               float* __restrict__ M) {
    if (threadIdx.x != 0 || blockIdx.x != 0) return;

    float Z[NS][NS], u[NS], v[NS];
    for (int i = 0; i < NS; ++i)
        for (int j = 0; j < NS; ++j)
            Z[i][j] = Hres_logits[i * NS + j] / TAU;

    const float logm = -logf((float)NS);
    for (int i = 0; i < NS; ++i) { u[i] = 0.f; v[i] = 0.f; }

    for (int it = 0; it < SINKHORN_ITERS; ++it) {
        for (int i = 0; i < NS; ++i) {
            float mx = -INFINITY;
            for (int j = 0; j < NS; ++j) mx = fmaxf(mx, Z[i][j] + v[j]);
            float s = 0.f;
            for (int j = 0; j < NS; ++j) s += expf(Z[i][j] + v[j] - mx);
            u[i] = logm - (mx + logf(s));
        }
        for (int j = 0; j < NS; ++j) {
            float mx = -INFINITY;
            for (int i = 0; i < NS; ++i) mx = fmaxf(mx, Z[i][j] + u[i]);
            float s = 0.f;
            for (int i = 0; i < NS; ++i) s += expf(Z[i][j] + u[i] - mx);
            v[j] = logm - (mx + logf(s));
        }
    }

    float Hres[NS][NS];
    for (int i = 0; i < NS; ++i)
        for (int j = 0; j < NS; ++j)
            Hres[i][j] = expf(Z[i][j] + u[i] + v[j]) * (float)NS;

    float hp[NS], mx = -INFINITY, s = 0.f;
    for (int i = 0; i < NS; ++i) mx = fmaxf(mx, Hpre_logits[i]);
    for (int i = 0; i < NS; ++i) { hp[i] = expf(Hpre_logits[i] - mx); s += hp[i]; }
    for (int i = 0; i < NS; ++i) hp[i] /= s;

    float ho[NS];
    mx = -INFINITY; s = 0.f;
    for (int i = 0; i < NS; ++i) mx = fmaxf(mx, Hpost_logits[i]);
    for (int i = 0; i < NS; ++i) { ho[i] = expf(Hpost_logits[i] - mx); s += ho[i]; }
    for (int i = 0; i < NS; ++i) ho[i] /= s;

    for (int so = 0; so < NS; ++so)
        for (int si = 0; si < NS; ++si)
            M[so * NS + si] = Hres[si][so] + ho[so] * hp[si];
}

// ---------------------------------------------------------------------------
// Kernel 2 (fast path): block-contiguous remap (R5) + plain loads + NT stores
// (R7 policy). Block bk owns positions pos = bk*1024 + k*256 + tid, k=0..3.
// Batch index b = bk>>11 is block-uniform (scalar base). Each block reads 4
// contiguous 16KB regions and NT-writes 4 contiguous 16KB regions.
// ---------------------------------------------------------------------------
__global__ __launch_bounds__(256) void hc_mix_flat(
        const f32x4* __restrict__ in,
        const float* __restrict__ Mg,
        f32x4* __restrict__ out) {
    float m[16];
#pragma unroll
    for (int k = 0; k < 16; ++k) m[k] = Mg[k];

    const long bb   = blockIdx.x >> 11;                       // batch (0..1), uniform
    const long q    = ((long)(blockIdx.x & 2047) << 10) + threadIdx.x;
    const long base = bb * (NS * PLANE4) + q;                 // + s*PLANE4 + k*256

    f32x4 v[4][NS];
#pragma unroll
    for (int k = 0; k < 4; ++k)
#pragma unroll
        for (int s = 0; s < NS; ++s)
            v[k][s] = in[base + (long)s * PLANE4 + k * 256];

#pragma unroll
    for (int k = 0; k < 4; ++k)
#pragma unroll
        for (int o = 0; o < NS; ++o) {
            f32x4 r = m[o*4+0] * v[k][0] + m[o*4+1] * v[k][1] +
                      m[o*4+2] * v[k][2] + m[o*4+3] * v[k][3];
            __builtin_nontemporal_store(r, &out[base + (long)o * PLANE4 + k * 256]);
        }
}

// Generic fallback (any size), same math.
__global__ __launch_bounds__(256) void hc_mix_generic(
        const f32x4* __restrict__ in,
        const float* __restrict__ Mg,
        f32x4* __restrict__ out,
        int npos4) {
    float m[16];
#pragma unroll
    for (int k = 0; k < 16; ++k) m[k] = Mg[k];

    const int stride = gridDim.x * blockDim.x;
    for (int p = blockIdx.x * blockDim.x + threadIdx.x; p < npos4; p += stride) {
        const int b = p >> PLANE4_SHIFT;
        const long base = ((long)(b * NS) << PLANE4_SHIFT) + (p & (PLANE4 - 1));
        const f32x4 v0 = in[base];
        const f32x4 v1 = in[base + PLANE4];
        const f32x4 v2 = in[base + 2 * PLANE4];
        const f32x4 v3 = in[base + 3 * PLANE4];
#pragma unroll
        for (int o = 0; o < NS; ++o) {
            f32x4 r = m[o*4+0]*v0 + m[o*4+1]*v1 + m[o*4+2]*v2 + m[o*4+3]*v3;
            __builtin_nontemporal_store(r, &out[base + (long)o * PLANE4]);
        }
    }
}

extern "C" void kernel_launch(void* const* d_in, const int* in_sizes, int n_in,
                              void* d_out, int out_size, void* d_ws, size_t ws_size,
                              hipStream_t stream) {
    const float* residuals   = (const float*)d_in[0];  // (B*S, T, D) = (8,4096,2048) f32
    const float* Hres_logits = (const float*)d_in[1];  // (4,4)
    const float* Hpre_logits = (const float*)d_in[2];  // (4,)
    const float* Hpost_logits= (const float*)d_in[3];  // (4,)
    float* out = (float*)d_out;
    float* M   = (float*)d_ws;                         // 16 floats

    hc_coef_kernel<<<1, 64, 0, stream>>>(Hres_logits, Hpre_logits, Hpost_logits, M);

    const int npos4 = out_size / (NS * 4);             // B*T*D/4 = 4194304
    if (npos4 == 4 * NTHREADS) {
        hc_mix_flat<<<NTHREADS / 256, 256, 0, stream>>>(
            (const f32x4*)residuals, M, (f32x4*)out);
    } else {
        hc_mix_generic<<<2048, 256, 0, stream>>>(
            (const f32x4*)residuals, M, (f32x4*)out, npos4);
    }
}